// Round 10
// baseline (193.009 us; speedup 1.0000x reference)
//
#include <hip/hip_runtime.h>
#include <hip/hip_bf16.h>

// ---------------------------------------------------------------------------
// QuixerCore: 10-qubit QSVT/LCU quantum circuit simulator.
// R4: tiled params GEMM. R12/R13: rolled-interpreter fused final.
// R14: LDS-state interpreter in pqc_step — REGRESSED (78us: 6.3M bank
//      conflicts; low-stride LDS pairing).
// R16: unrolled register PQC = 151.3us. R17/R18: cooperative fusion DEAD
//      (grid.sync ~200us each). R19: atomic slice accumulation, 4 dispatches,
//      148.5us — launch tax measured tiny (graph capture), so time is INSIDE
//      pqc_step (~35-40us each vs ~12us arithmetic floor; ~24KB straight-line
//      body => instruction-fetch streaming serializes with execution).
// R20: SHUFFLE-INTERPRETER pqc_step — rolled loop, state in registers,
//      pairing via __shfl_xor with RUNTIME mask for the 6 lane-bit wires
//      (no dynamic register indexing), 4 small static variants for the 4
//      register-bit wires. Canonical layout (R14-verified): zero remaps,
//      zero LDS in the gate chain, zero barriers, zero bank conflicts,
//      ~6KB looped code vs 24KB straight-line. params_kernel / final_fused
//      byte-identical to R19 (one lever per round).
// Canonical layout: flat index n = r*64+lane (r = regs bits 6..9,
// lane = bits 0..5), wire w at bit (9-w).
// ---------------------------------------------------------------------------

#define NQ   10
#define NT   32
#define DM   512
#define BATCH 128
#define NPQC 40
#define DIM  1024
#define SLICE_V2F (BATCH * DIM)   // 131072 v2f = 1 MB per accumulated slice

typedef float v2f __attribute__((ext_vector_type(2)));

__device__ __forceinline__ v2f Jrot(v2f v) {   // -i*v = (v.y, -v.x)
  return __builtin_shufflevector(v, -v, 1, 2);
}
__device__ __forceinline__ v2f Jc(v2f v) {     // +i*v = (-v.y, v.x)
  return __builtin_shufflevector(-v, v, 1, 2);
}

// ------------------------- register-bit gate variants -----------------------
// M = register-bit mask (1,2,4,8) for target wire on reg bit log2(M).

template<int M>
__device__ __forceinline__ void ry_reg(v2f (&a)[16], float c, float s) {
#pragma unroll
  for (int r = 0; r < 16; ++r) {
    if (!(r & M)) {
      int r1 = r | M;
      v2f a0 = a[r], a1 = a[r1];
      a[r]  = c * a0 - s * a1;
      a[r1] = s * a0 + c * a1;
    }
  }
}

template<int M>
__device__ __forceinline__ void crx_reg(v2f (&a)[16], int lane, int cb,
                                        float c, float s) {
#pragma unroll
  for (int r = 0; r < 16; ++r) {
    if (!(r & M)) {
      int r1 = r | M;
      // control bit cb of flat index n = (r<<6)|lane (cb != target bit,
      // so both pair members share the control value)
      int en = (cb >= 6) ? ((r >> (cb - 6)) & 1) : ((lane >> cb) & 1);
      float ce = en ? c : 1.f;
      float se = en ? s : 0.f;
      v2f a0 = a[r], a1 = a[r1];
      a[r]  = ce * a0 + se * Jrot(a1);
      a[r1] = ce * a1 + se * Jrot(a0);
    }
  }
}

// ------------------------- rolled shuffle interpreter -----------------------
// Gate table (ansatz14, q=10): k in
//   [ 0,10): RY  target k
//   [10,20): CRX control i=19-k, target (i+1)%10
//   [20,30): RY  target k-20
//   [30,40): CRX i = (k==30 ? 9 : k-31), control i, target (i+9)%10
// Wire w <-> bit (9-w). tb/cb are bit positions; tb>=6 -> register pairing
// (static variants), tb<6 -> lane pairing via __shfl_xor (runtime mask).
template<int K0>
__device__ __forceinline__ void run_circuit(v2f (&a)[16],
    const float2* __restrict__ angs, int lane) {
  float2 th = angs[K0];
#pragma unroll 1
  for (int k = K0; k < NPQC; ++k) {
    float2 thn = angs[(k + 1 < NPQC) ? k + 1 : k];   // prefetch next angle
    int isCrx, tb, cb;
    {
      int c, t;
      if (k < 10)      { isCrx = 0; t = k;      c = 0; }
      else if (k < 20) { int i = 19 - k; isCrx = 1; c = i; t = (i == 9) ? 0 : i + 1; }
      else if (k < 30) { isCrx = 0; t = k - 20; c = 0; }
      else             { int i = (k == 30) ? 9 : k - 31; isCrx = 1; c = i; t = (i == 0) ? 9 : i - 1; }
      tb = 9 - t;
      cb = 9 - c;
    }
    float cg = th.x, sg = th.y;

    if (tb >= 6) {
      // register-bit target: 4 static variants (wave-uniform switch)
      if (!isCrx) {
        switch (tb) {
          case 6:  ry_reg<1>(a, cg, sg); break;
          case 7:  ry_reg<2>(a, cg, sg); break;
          case 8:  ry_reg<4>(a, cg, sg); break;
          default: ry_reg<8>(a, cg, sg); break;
        }
      } else {
        switch (tb) {
          case 6:  crx_reg<1>(a, lane, cb, cg, sg); break;
          case 7:  crx_reg<2>(a, lane, cb, cg, sg); break;
          case 8:  crx_reg<4>(a, lane, cb, cg, sg); break;
          default: crx_reg<8>(a, lane, cb, cg, sg); break;
        }
      }
    } else {
      // lane-bit target: partner via shuffle, runtime mask
      int lm = 1 << tb;
      if (!isCrx) {
        // RY: bit0 lane: a' = c*own - s*p ; bit1 lane: a' = c*own + s*p
        int bit = (lane >> tb) & 1;
        float ss = bit ? sg : -sg;
#pragma unroll
        for (int r = 0; r < 16; ++r) {
          float px = __shfl_xor(a[r].x, lm);
          float py = __shfl_xor(a[r].y, lm);
          a[r].x = cg * a[r].x + ss * px;
          a[r].y = cg * a[r].y + ss * py;
        }
      } else if (cb < 6) {
        // CRX, lane control: a' = ce*own + se*Jrot(p) (symmetric)
        int en = (lane >> cb) & 1;
        float ce = en ? cg : 1.f;
        float se = en ? sg : 0.f;
#pragma unroll
        for (int r = 0; r < 16; ++r) {
          float px = __shfl_xor(a[r].x, lm);
          float py = __shfl_xor(a[r].y, lm);
          a[r].x = ce * a[r].x + se * py;
          a[r].y = ce * a[r].y - se * px;
        }
      } else {
        // CRX, register control: enable depends on r only (uniform per r)
        int csh = cb - 6;
#pragma unroll
        for (int r = 0; r < 16; ++r) {
          float px = __shfl_xor(a[r].x, lm);
          float py = __shfl_xor(a[r].y, lm);
          int en = (r >> csh) & 1;
          float ce = en ? cg : 1.f;
          float se = en ? sg : 0.f;
          a[r].x = ce * a[r].x + se * py;
          a[r].y = ce * a[r].y - se * px;
        }
      }
    }
    th = thn;
  }
}

// ------------------------- params GEMM + slice zeroing ----------------------
// blocks 0..255: 16-row GEMM tile -> cs angles
// block  256   : ffcs + lcu normalization
// blocks 257..1280: zero part1/part2 slice 0 (2 MB) for atomic accumulation
__global__ __launch_bounds__(256) void params_kernel(
    const float* __restrict__ emb, const float* __restrict__ W,
    const float* __restrict__ bias,
    const float* __restrict__ lcu_re, const float* __restrict__ lcu_im,
    const float* __restrict__ ffp,
    float2* __restrict__ cs, float2* __restrict__ ffcs, float2* __restrict__ lcu,
    v2f* __restrict__ part1, v2f* __restrict__ part2) {
  int blk = blockIdx.x;
  int tid = threadIdx.x;
  if (blk >= 257) {
    int idx = (blk - 257) * 256 + tid;   // [0, 262144)
    v2f z = (v2f)(0.f);
    if (idx < SLICE_V2F) part1[idx] = z;
    else                 part2[idx - SLICE_V2F] = z;
    return;
  }
  if (blk == 256) {
    if (tid < NPQC) {
      float h = 0.5f * ffp[tid];
      ffcs[tid] = make_float2(cosf(h), sinf(h));
    }
    if (tid == 64) {
      float ssum = 0.f;
      for (int i = 0; i < NT; ++i) {
        float re = lcu_re[i], im = lcu_im[i];
        ssum += sqrtf(re * re + im * im);
      }
      float inv = 1.f / ssum;
      for (int i = 0; i < NT; ++i)
        lcu[i] = make_float2(lcu_re[i] * inv, lcu_im[i] * inv);
    }
    return;
  }

  __shared__ float Asl[16 * 516];   // 33 KB; reused as reduction buffer
  int row0 = blk * 16;

  const float4* eg = (const float4*)(emb + (size_t)row0 * DM);
#pragma unroll
  for (int i = 0; i < 8; ++i) {
    int e = tid + i * 256;
    int r = e >> 7, k4 = e & 127;
    float4 v = eg[e];
    *(float4*)&Asl[r * 516 + k4 * 4] = v;
  }
  __syncthreads();

  int kq = tid >> 6;
  int lane = tid & 63;
  int rg = lane >> 3;
  int cg = lane & 7;

  const float* Ar0 = &Asl[(2 * rg) * 516 + kq * 128];
  const float* Ar1 = Ar0 + 516;
  const float* Bg  = W + (size_t)(5 * cg) * DM + kq * 128;

  float acc[2][5] = {};
#pragma unroll 4
  for (int k = 0; k < 128; k += 4) {
    float4 a0 = *(const float4*)(Ar0 + k);
    float4 a1 = *(const float4*)(Ar1 + k);
#pragma unroll
    for (int j = 0; j < 5; ++j) {
      float4 b = *(const float4*)(Bg + j * DM + k);
      acc[0][j] += a0.x * b.x + a0.y * b.y + a0.z * b.z + a0.w * b.w;
      acc[1][j] += a1.x * b.x + a1.y * b.y + a1.z * b.z + a1.w * b.w;
    }
  }

  __syncthreads();
  float* red = Asl;
#pragma unroll
  for (int i = 0; i < 2; ++i)
#pragma unroll
    for (int j = 0; j < 5; ++j)
      red[kq * 644 + (2 * rg + i) * 40 + 5 * cg + j] = acc[i][j];
  __syncthreads();

  for (int o = tid; o < 640; o += 256) {
    float v = bias[o % 40] + red[o] + red[644 + o] + red[1288 + o] + red[1932 + o];
    float h = 0.5f * v;
    cs[(size_t)blk * 640 + o] = make_float2(cosf(h), sinf(h));
  }
}

// ------------------------- QSVT step (shuffle interpreter) ------------------
// grid = 1024 (b = blk>>3, qq = blk&7), block = 256 = 4 waves, wave wv ->
// token l = qq*4+wv. Each wave: canonical register state, rolled shuffle
// interpreter (no LDS/barriers in the gate chain). Epilogue: weighted 4-slab
// sum atomically accumulated into slice dst[b] (zeroed in params_kernel).
template<bool FIRST>
__global__ __launch_bounds__(256) void pqc_step(
    const float2* __restrict__ cs, const float2* __restrict__ lcu,
    const v2f* __restrict__ src, v2f* __restrict__ dst) {
  __shared__ v2f slabs[4][1024];   // 32 KB
  int tid = threadIdx.x;
  int lane = tid & 63;
  int wvu = __builtin_amdgcn_readfirstlane(tid >> 6);
  int blk = blockIdx.x;
  int b = blk >> 3, qq = blk & 7;
  int l = qq * 4 + wvu;
  const float2* csrow = cs + (size_t)(b * NT + l) * NPQC;
  v2f* slab = slabs[wvu];

  v2f a[16];
  if constexpr (FIRST) {
    // canonical product state: amp[n] = prod_b csrow[9-b][(n>>b)&1]
    // (first 10 RYs folded into init; interpreter starts at k=10)
    float2 f9 = csrow[9], f8 = csrow[8], f7 = csrow[7], f6 = csrow[6];
    float2 f5 = csrow[5], f4 = csrow[4], f3 = csrow[3], f2 = csrow[2];
    float2 f1 = csrow[1], f0 = csrow[0];
    float lp = ((lane & 1) ? f9.y : f9.x);
    lp *= ((lane & 2)  ? f8.y : f8.x);
    lp *= ((lane & 4)  ? f7.y : f7.x);
    lp *= ((lane & 8)  ? f6.y : f6.x);
    lp *= ((lane & 16) ? f5.y : f5.x);
    lp *= ((lane & 32) ? f4.y : f4.x);
#pragma unroll
    for (int r = 0; r < 16; ++r) {
      float rp = ((r & 1) ? f3.y : f3.x) * ((r & 2) ? f2.y : f2.x)
               * ((r & 4) ? f1.y : f1.x) * ((r & 8) ? f0.y : f0.x);
      a[r].x = lp * rp;
      a[r].y = 0.f;
    }
  } else {
    const v2f* s = src + (size_t)b * DIM;
#pragma unroll
    for (int r = 0; r < 16; ++r) a[r] = s[r * 64 + lane];
  }

  run_circuit<FIRST ? 10 : 0>(a, csrow, lane);

  // weighted write into own slab (canonical index, bank-spread swizzle)
  float2 w = lcu[l];
#pragma unroll
  for (int r = 0; r < 16; ++r) {
    int n = r * 64 + lane;
    slab[n ^ (n >> 5)] = w.x * a[r] + w.y * Jc(a[r]);
  }
  __syncthreads();

  // 4-slab block reduction -> atomic accumulate into slice dst[b]
  float* df = (float*)(dst + (size_t)b * DIM);
#pragma unroll
  for (int i = 0; i < 4; ++i) {
    int n = tid + i * 256;
    int ph = n ^ (n >> 5);
    v2f sum = slabs[0][ph] + slabs[1][ph] + slabs[2][ph] + slabs[3][ph];
    atomicAdd(df + 2 * n,     sum.x);
    atomicAdd(df + 2 * n + 1, sum.y);
  }
}

// ------------------------- fused final (R19 verbatim) -----------------------
// One block (256 thr = 4 waves) per batch element:
//   A) state = normalize(q0*e0 + q1*red1[b] + q2*red2[b]) -> LDS
//   B) 40-gate rolled interpreter (2 pairs/thread, barrier per gate)
//   C) rolled 10-wire measurement, wave-shuffle reduced.
__global__ __launch_bounds__(256) void final_fused(
    const v2f* __restrict__ red1, const v2f* __restrict__ red2b,
    const float* __restrict__ qsvt, const float2* __restrict__ ffcs,
    float* __restrict__ out) {
  __shared__ v2f st[1024];        // 8 KB state
  __shared__ float2 ang[40];
  __shared__ float rbuf[4];
  __shared__ float red2[120];
  int b = blockIdx.x, tid = threadIdx.x;
  int lane = tid & 63, wvu = tid >> 6;
  float q0 = qsvt[0], q1 = qsvt[1], q2 = qsvt[2];
  const v2f* r1 = red1 + (size_t)b * DIM;
  const v2f* p2 = red2b + (size_t)b * DIM;

  if (tid < NPQC) ang[tid] = ffcs[tid];

  // ---- A: combine + normalize into LDS ----
  v2f vals[4];
  float nn = 0.f;
#pragma unroll
  for (int i = 0; i < 4; ++i) {
    int n = tid + i * 256;
    v2f v = q1 * r1[n] + q2 * p2[n];
    if (n == 0) v.x += q0;
    vals[i] = v;
    nn += v.x * v.x + v.y * v.y;
  }
#pragma unroll
  for (int o = 1; o < 64; o <<= 1) nn += __shfl_xor(nn, o);
  if (lane == 0) rbuf[wvu] = nn;
  __syncthreads();
  float inv = 1.f / sqrtf(rbuf[0] + rbuf[1] + rbuf[2] + rbuf[3]);
#pragma unroll
  for (int i = 0; i < 4; ++i) {
    int n = tid + i * 256;
    st[n ^ (n >> 5)] = vals[i] * inv;
  }
  __syncthreads();

  // ---- B: 40-gate interpreter (rolled, block-cooperative) ----
#pragma unroll 1
  for (int k = 0; k < NPQC; ++k) {
    int isCrx, c, t;
    if (k < 10)      { isCrx = 0; t = k;      c = 0; }
    else if (k < 20) { int i = 19 - k; isCrx = 1; c = i; t = (i == 9) ? 0 : i + 1; }
    else if (k < 30) { isCrx = 0; t = k - 20; c = 0; }
    else             { int i = (k == 30) ? 9 : k - 31; isCrx = 1; c = i; t = (i == 0) ? 9 : i - 1; }
    int m  = 1 << (9 - t);
    int cb = 9 - c;
    float2 th = ang[k];
    float cg = th.x, sg = th.y;

    v2f a0[2], a1[2];
    int j0[2], j1[2], en[2];
#pragma unroll
    for (int p = 0; p < 2; ++p) {
      int qp = p * 256 + tid;                       // pair index 0..511
      int i0 = ((qp & ~(m - 1)) << 1) | (qp & (m - 1));
      int i1 = i0 | m;
      j0[p] = i0 ^ (i0 >> 5);
      j1[p] = i1 ^ (i1 >> 5);
      en[p] = (i0 >> cb) & 1;
      a0[p] = st[j0[p]];
      a1[p] = st[j1[p]];
    }
#pragma unroll
    for (int p = 0; p < 2; ++p) {
      v2f n0, n1;
      if (!isCrx) {
        n0 = cg * a0[p] - sg * a1[p];
        n1 = sg * a0[p] + cg * a1[p];
      } else {
        float ce = en[p] ? cg : 1.f;
        float se = en[p] ? sg : 0.f;
        n0 = ce * a0[p] + se * Jrot(a1[p]);
        n1 = ce * a1[p] + se * Jrot(a0[p]);
      }
      st[j0[p]] = n0;
      st[j1[p]] = n1;
    }
    __syncthreads();   // gate k writes visible before gate k+1 reads
  }

  // ---- C: measurement — per-thread partials, wave-shuffle reduce ----
  float prt[30];
#pragma unroll
  for (int w = 0; w < NQ; ++w) {
    int m = 1 << (9 - w);
    float xr = 0.f, xi = 0.f, zz = 0.f;
#pragma unroll
    for (int p = 0; p < 2; ++p) {
      int qp = p * 256 + tid;
      int i0 = ((qp & ~(m - 1)) << 1) | (qp & (m - 1));
      int i1 = i0 | m;
      v2f a0 = st[i0 ^ (i0 >> 5)];
      v2f a1 = st[i1 ^ (i1 >> 5)];
      xr += a0.x * a1.x + a0.y * a1.y;
      xi += a0.x * a1.y - a0.y * a1.x;
      zz += a0.x * a0.x + a0.y * a0.y - a1.x * a1.x - a1.y * a1.y;
    }
    prt[w]      = xr;
    prt[10 + w] = xi;
    prt[20 + w] = zz;
  }
#pragma unroll
  for (int v = 0; v < 30; ++v) {
#pragma unroll
    for (int o = 1; o < 64; o <<= 1) prt[v] += __shfl_xor(prt[v], o);
  }
  if (lane == 0) {
#pragma unroll
    for (int v = 0; v < 30; ++v) red2[wvu * 30 + v] = prt[v];
  }
  __syncthreads();
  if (tid < 30) {
    float s2 = red2[tid] + red2[30 + tid] + red2[60 + tid] + red2[90 + tid];
    float sc = (tid < 20) ? 2.f : 1.f;
    out[b * 30 + tid] = sc * s2;
  }
}

// ------------------------- launch ------------------------------------------

extern "C" void kernel_launch(void* const* d_in, const int* in_sizes, int n_in,
                              void* d_out, int out_size, void* d_ws, size_t ws_size,
                              hipStream_t stream) {
  const float* emb    = (const float*)d_in[0];
  const float* W      = (const float*)d_in[1];
  const float* bias   = (const float*)d_in[2];
  const float* lcu_re = (const float*)d_in[3];
  const float* lcu_im = (const float*)d_in[4];
  const float* qsvt   = (const float*)d_in[5];
  const float* ffp    = (const float*)d_in[6];
  float* out = (float*)d_out;

  char* ws = (char*)d_ws;
  // cs[4096][40] f2 | ffcs[40] | lcu[32] | pad |
  // part1[128][1024] v2f (1 MB, atomic-accumulated) | part2[128][1024] v2f
  float2* cs    = (float2*)ws;                               // 1,310,720 B
  float2* ffcs  = (float2*)(ws + 1310720);                   //       320 B
  float2* lcu   = (float2*)(ws + 1311040);                   //       256 B
  v2f*    part1 = (v2f*)(ws + 1311744);                      // 1,048,576 B
  v2f*    part2 = (v2f*)(ws + 1311744 + 1048576);            // 1,048,576 B

  params_kernel<<<1281, 256, 0, stream>>>(emb, W, bias, lcu_re, lcu_im, ffp,
                                          cs, ffcs, lcu, part1, part2);
  pqc_step<true><<<1024, 256, 0, stream>>>(cs, lcu, nullptr, part1);
  pqc_step<false><<<1024, 256, 0, stream>>>(cs, lcu, part1, part2);
  final_fused<<<BATCH, 256, 0, stream>>>(part1, part2, qsvt, ffcs, out);
}